// Round 4
// baseline (726.035 us; speedup 1.0000x reference)
//
#include <hip/hip_runtime.h>

#define Bn 128
#define Sn 512
#define Hn 1024
#define Ln 4

typedef float nfloat4 __attribute__((ext_vector_type(4)));

__device__ __forceinline__ float sigmoidf_(float x) { return 1.0f / (1.0f + __expf(-x)); }

// ---------------- K1: fused lengths + stable descending argsort (1 block) ----------------
__global__ __launch_bounds__(1024) void lensort_kernel(const int* __restrict__ x,
                                                       int* __restrict__ lengths,
                                                       int* __restrict__ rank,
                                                       int* __restrict__ tok_sorted,
                                                       int* __restrict__ bs_last,
                                                       int* __restrict__ cnt) {
  __shared__ int pc[128][8];
  __shared__ int sl[128];
  __shared__ int scnt;
  const int t = threadIdx.x;
  const int row = t >> 3, seg = t & 7;
  // phase 1: count x>0 per row (8 threads per row, 16 int4 each)
  int c = 0;
  const int4* xp = (const int4*)x + row * 128 + seg * 16;
#pragma unroll
  for (int i = 0; i < 16; i++) {
    int4 v = xp[i];
    c += (v.x > 0) + (v.y > 0) + (v.z > 0) + (v.w > 0);
  }
  pc[row][seg] = c;
  if (t == 0) scnt = 0;
  if (t < 4) cnt[t] = 0;          // per-layer gemm completion counters
  __syncthreads();
  // phase 2: lengths, rank, sorted first tokens, bs_last (threads 0..127)
  int len = 0;
  if (t < 128) {
#pragma unroll
    for (int i = 0; i < 8; i++) len += pc[t][i];
    sl[t] = len;
    lengths[t] = len;
  }
  __syncthreads();
  if (t < 128) {
    int r = 0;
    for (int b2 = 0; b2 < 128; b2++) {
      int l2 = sl[b2];
      r += (l2 > len) || (l2 == len && b2 < t);
    }
    rank[t] = r;                 // unsort_idx[t]
    tok_sorted[r] = x[t * Sn];   // x[sorted_idx[r], 0]
    if (len >= Sn) atomicAdd(&scnt, 1);
  }
  __syncthreads();
  if (t == 0) bs_last[0] = scnt;
}

// ---------------- K2: split-K GEMM + fused reduction/activation ----------------
// grid = 32 m-tiles x 8 k-chunks = 256 blocks (1/CU, all co-resident), 256 threads (4 waves).
// Phase 1 (R1-proven body): thread owns 4 rows x 12 gate cols; partials[kc][q][m][r].
// Phase 2: device-scope counter barrier (threadfence release + atomicAdd; t0 spins to 256;
//          threadfence acquire), then each block reduces m0=blockIdx*4 exactly like the old
//          act_kernel (kc split 4+4 across thread halves, combined in LDS).
__global__ __launch_bounds__(256) void gemm_fused(const float* __restrict__ xt,
                                                  const int* __restrict__ tok,
                                                  const float* __restrict__ Wl,
                                                  float* __restrict__ part,
                                                  const float* __restrict__ bih,
                                                  const float* __restrict__ bhh,
                                                  const int* __restrict__ bs_last,
                                                  int* __restrict__ cnt,
                                                  float* __restrict__ xt_out,
                                                  float* __restrict__ sh,
                                                  float* __restrict__ sc) {
  __shared__ float xtT[32][132];  // [kk][r], stride 132 keeps 16B alignment for b128 reads
  __shared__ float Ws[32][96];    // [kk][q*32 + mloc]
  __shared__ int sTok[128];
  __shared__ float red[128][12];  // reduction combine buffer (phase 2)
  const int t = threadIdx.x;
  const int mtile = blockIdx.x & 31;
  const int kc = blockIdx.x >> 5;
  const int rg = t & 31;
  const int msub = t >> 5;     // 0..7 -> m_loc = msub*4..+3
  const int k0 = kc * 128;
  const int kv4 = (t & 7) * 4;

  if (tok != nullptr) {        // uniform branch; layer 0 only
    if (t < 128) sTok[t] = tok[t];
    __syncthreads();
  }

  const float* xrow[4];
#pragma unroll
  for (int i = 0; i < 4; i++) {
    const int r = i * 32 + (t >> 3);
    const int row = (tok != nullptr) ? sTok[r] : r;
    xrow[i] = xt + (size_t)row * 1024;
  }

  float acc[3][4][4];
#pragma unroll
  for (int q = 0; q < 3; q++)
#pragma unroll
    for (int mm = 0; mm < 4; mm++)
#pragma unroll
      for (int rr = 0; rr < 4; rr++) acc[q][mm][rr] = 0.0f;

  float4 xreg[4], wreg[3];
  // prologue: load tile 0 into registers
  {
#pragma unroll
    for (int i = 0; i < 4; i++) xreg[i] = *(const float4*)&xrow[i][k0 + kv4];
#pragma unroll
    for (int i = 0; i < 3; i++) {
      int jj = i * 32 + (t >> 3);
      int q = jj >> 5, mloc = jj & 31;
      int qoff = (q == 0) ? 0 : ((q == 1) ? 2048 : 3072);  // gate rows: i, g, o
      wreg[i] = *(const float4*)&Wl[(size_t)(qoff + mtile * 32 + mloc) * 1024 + k0 + kv4];
    }
  }

#pragma unroll
  for (int tile = 0; tile < 4; tile++) {
    __syncthreads();
    // registers -> LDS (transposed)
#pragma unroll
    for (int i = 0; i < 4; i++) {
      const int r = i * 32 + (t >> 3);
      xtT[kv4 + 0][r] = xreg[i].x;
      xtT[kv4 + 1][r] = xreg[i].y;
      xtT[kv4 + 2][r] = xreg[i].z;
      xtT[kv4 + 3][r] = xreg[i].w;
    }
#pragma unroll
    for (int i = 0; i < 3; i++) {
      const int jj = i * 32 + (t >> 3);
      Ws[kv4 + 0][jj] = wreg[i].x;
      Ws[kv4 + 1][jj] = wreg[i].y;
      Ws[kv4 + 2][jj] = wreg[i].z;
      Ws[kv4 + 3][jj] = wreg[i].w;
    }
    // prefetch next tile while computing this one
    float4 xnxt[4], wnxt[3];
    if (tile < 3) {
      const int kt = k0 + (tile + 1) * 32;
#pragma unroll
      for (int i = 0; i < 4; i++) xnxt[i] = *(const float4*)&xrow[i][kt + kv4];
#pragma unroll
      for (int i = 0; i < 3; i++) {
        int jj = i * 32 + (t >> 3);
        int q = jj >> 5, mloc = jj & 31;
        int qoff = (q == 0) ? 0 : ((q == 1) ? 2048 : 3072);
        wnxt[i] = *(const float4*)&Wl[(size_t)(qoff + mtile * 32 + mloc) * 1024 + kt + kv4];
      }
    }
    __syncthreads();
#pragma unroll
    for (int kk = 0; kk < 32; kk++) {
      const float4 xv = *(const float4*)&xtT[kk][rg * 4];
      const float4 w0 = *(const float4*)&Ws[kk][msub * 4];
      const float4 w1 = *(const float4*)&Ws[kk][32 + msub * 4];
      const float4 w2 = *(const float4*)&Ws[kk][64 + msub * 4];
      const float xa[4] = {xv.x, xv.y, xv.z, xv.w};
      const float wv[3][4] = {{w0.x, w0.y, w0.z, w0.w},
                              {w1.x, w1.y, w1.z, w1.w},
                              {w2.x, w2.y, w2.z, w2.w}};
#pragma unroll
      for (int q = 0; q < 3; q++)
#pragma unroll
        for (int mm = 0; mm < 4; mm++)
#pragma unroll
          for (int rr = 0; rr < 4; rr++)
            acc[q][mm][rr] = fmaf(wv[q][mm], xa[rr], acc[q][mm][rr]);
    }
    if (tile < 3) {
#pragma unroll
      for (int i = 0; i < 4; i++) xreg[i] = xnxt[i];
#pragma unroll
      for (int i = 0; i < 3; i++) wreg[i] = wnxt[i];
    }
  }

  const int mbase = mtile * 32 + msub * 4;
#pragma unroll
  for (int q = 0; q < 3; q++)
#pragma unroll
    for (int mm = 0; mm < 4; mm++) {
      float4 v = make_float4(acc[q][mm][0], acc[q][mm][1], acc[q][mm][2], acc[q][mm][3]);
      *(float4*)&part[(((size_t)kc * 3 + q) * 1024 + (mbase + mm)) * 128 + rg * 4] = v;
    }

  // ---------------- phase 2: device-scope completion barrier ----------------
  __threadfence();            // release: partial stores -> agent-visible (cross-XCD)
  __syncthreads();            // all waves' stores fenced before the block is counted
  if (t == 0) {
    atomicAdd(cnt, 1);
    while (__hip_atomic_load(cnt, __ATOMIC_RELAXED, __HIP_MEMORY_SCOPE_AGENT) < 256) {}
  }
  __syncthreads();
  __threadfence();            // acquire: no stale cached partials

  // ---------------- phase 3: reduce + activations (old act_kernel, kc split 4+4) ----------
  const int r = t & 127;
  const int half = t >> 7;    // 0: kc 0-3, 1: kc 4-7
  const int m0 = blockIdx.x * 4;   // 256 blocks -> m in [0,1024) exactly
  float s[3][4];
#pragma unroll
  for (int q = 0; q < 3; q++)
#pragma unroll
    for (int mm = 0; mm < 4; mm++) s[q][mm] = 0.0f;
#pragma unroll
  for (int k4 = 0; k4 < 4; k4++) {
    const int kcc = half * 4 + k4;
#pragma unroll
    for (int q = 0; q < 3; q++)
#pragma unroll
      for (int mm = 0; mm < 4; mm++)
        s[q][mm] += part[(((size_t)kcc * 3 + q) * 1024 + (m0 + mm)) * 128 + r];
  }
  if (half == 1) {
#pragma unroll
    for (int q = 0; q < 3; q++)
#pragma unroll
      for (int mm = 0; mm < 4; mm++) red[r][q * 4 + mm] = s[q][mm];
  }
  __syncthreads();
  if (half == 0) {
    const int bs = bs_last[0];
    float hv[4], cv[4];
#pragma unroll
    for (int mm = 0; mm < 4; mm++) {
      const int m = m0 + mm;
      const float si = s[0][mm] + red[r][0 * 4 + mm] + bih[m] + bhh[m];
      const float sg = s[1][mm] + red[r][1 * 4 + mm] + bih[2048 + m] + bhh[2048 + m];
      const float so = s[2][mm] + red[r][2 * 4 + mm] + bih[3072 + m] + bhh[3072 + m];
      const float c = sigmoidf_(si) * tanhf(sg);
      const float h = sigmoidf_(so) * tanhf(c);
      hv[mm] = h;
      cv[mm] = c;
    }
    const float msk = (r < bs) ? 1.0f : 0.0f;
    *(float4*)&xt_out[(size_t)r * 1024 + m0] = make_float4(hv[0], hv[1], hv[2], hv[3]);
    *(float4*)&sh[(size_t)r * 1024 + m0] =
        make_float4(msk * hv[0], msk * hv[1], msk * hv[2], msk * hv[3]);
    *(float4*)&sc[(size_t)r * 1024 + m0] =
        make_float4(msk * cv[0], msk * cv[1], msk * cv[2], msk * cv[3]);
  }
}

// ---------------- K3: output[t,b,:] = (t < len[b]) ? h_final_sorted[rank[b],:] : 0 ----------------
// grid = 128 b x 8 t-chunks (64 t each), R1-proven full-write version.
__global__ __launch_bounds__(256) void bcast_kernel(const float* __restrict__ hfin,
                                                    const int* __restrict__ lengths,
                                                    const int* __restrict__ rank,
                                                    float* __restrict__ out) {
  const int b = blockIdx.x & 127;
  const int c = blockIdx.x >> 7;      // 0..7
  const int len = lengths[b];
  const int t0 = c * 64;
  nfloat4 v = (nfloat4)0.0f;
  if (t0 < len) v = ((const nfloat4*)hfin)[rank[b] * 256 + threadIdx.x];
  int valid = len - t0;
  valid = valid < 0 ? 0 : (valid > 64 ? 64 : valid);
  nfloat4* p = (nfloat4*)out + ((size_t)t0 * 128 + b) * 256 + threadIdx.x;
  for (int i = 0; i < valid; i++) {
    __builtin_nontemporal_store(v, p);
    p += 32768;                        // one t step = 128*1024 floats
  }
  const nfloat4 z = (nfloat4)0.0f;
  for (int i = valid; i < 64; i++) {
    __builtin_nontemporal_store(z, p);
    p += 32768;
  }
}

extern "C" void kernel_launch(void* const* d_in, const int* in_sizes, int n_in,
                              void* d_out, int out_size, void* d_ws, size_t ws_size,
                              hipStream_t stream) {
  const int* x = (const int*)d_in[0];
  const float* emb = (const float*)d_in[1];
  const float* W_ih = (const float*)d_in[2];
  // d_in[3] = W_hh: NEVER multiplied (h0 == 0); only b_hh is added.
  const float* b_ih = (const float*)d_in[4];
  const float* b_hh = (const float*)d_in[5];

  float* out = (float*)d_out;
  float* sh = out + (size_t)Sn * Bn * Hn;   // state_h [L,B,H]
  float* sc = sh + (size_t)Ln * Bn * Hn;    // state_c [L,B,H]
  float* part = out;                        // 12.58 MB GEMM-partial scratch inside the
                                            // output region; overwritten by bcast later.

  char* ws = (char*)d_ws;
  int* lengths = (int*)ws;                  // [128]
  int* rank = lengths + 128;                // [128]
  int* tok_sorted = rank + 128;             // [128]
  int* bs_last = tok_sorted + 128;          // [1]
  int* cnt = bs_last + 1;                   // [4] per-layer completion counters
  float* xtA = (float*)(ws + 4096);         // [128,1024]
  float* xtB = xtA + 128 * 1024;            // [128,1024]

  lensort_kernel<<<1, 1024, 0, stream>>>(x, lengths, rank, tok_sorted, bs_last, cnt);

  // layer 0 consumes emb rows gathered via tok_sorted directly
  float* bufs[2] = {xtA, xtB};
  const float* xin = emb;
  const int* tokp = tok_sorted;
  for (int l = 0; l < Ln; l++) {
    gemm_fused<<<256, 256, 0, stream>>>(xin, tokp, W_ih + (size_t)l * 4 * Hn * Hn, part,
                                        b_ih + l * 4 * Hn, b_hh + l * 4 * Hn, bs_last,
                                        cnt + l, bufs[l & 1], sh + (size_t)l * Bn * Hn,
                                        sc + (size_t)l * Bn * Hn);
    xin = bufs[l & 1];
    tokp = nullptr;
  }
  // after the loop, xin == xtB holds the top-layer h (sorted order)
  bcast_kernel<<<1024, 256, 0, stream>>>(xin, lengths, rank, out);
}

// Round 5
// 495.144 us; speedup vs baseline: 1.4663x; 1.4663x over previous
//
#include <hip/hip_runtime.h>

#define Bn 128
#define Sn 512
#define Hn 1024
#define Ln 4

typedef float nfloat4 __attribute__((ext_vector_type(4)));

__device__ __forceinline__ float sigmoidf_(float x) { return 1.0f / (1.0f + __expf(-x)); }

// ---------------- K1: lengths[b] = count(x[b,:] > 0) ----------------
__global__ __launch_bounds__(128) void len_kernel(const int* __restrict__ x, int* __restrict__ lengths) {
  const int b = blockIdx.x, t = threadIdx.x;
  int4 v = ((const int4*)x)[b * 128 + t];
  int c = (v.x > 0) + (v.y > 0) + (v.z > 0) + (v.w > 0);
  for (int off = 32; off > 0; off >>= 1) c += __shfl_down(c, off);
  __shared__ int tmp[2];
  if ((t & 63) == 0) tmp[t >> 6] = c;
  __syncthreads();
  if (t == 0) lengths[b] = tmp[0] + tmp[1];
}

// ------- K2: stable descending argsort rank, sorted first tokens, bs_last -------
__global__ __launch_bounds__(128) void sort_kernel(const int* __restrict__ x, const int* __restrict__ lengths,
                                                   int* __restrict__ rank, int* __restrict__ tok_sorted,
                                                   int* __restrict__ bs_last) {
  __shared__ int sl[128];
  __shared__ int cnt;
  const int b = threadIdx.x;
  const int len = lengths[b];
  sl[b] = len;
  if (b == 0) cnt = 0;
  __syncthreads();
  int r = 0;
  for (int b2 = 0; b2 < 128; b2++) {
    int l2 = sl[b2];
    r += (l2 > len) || (l2 == len && b2 < b);
  }
  rank[b] = r;                 // unsort_idx[b] = position of original row b in sorted order
  tok_sorted[r] = x[b * Sn];   // x[sorted_idx[r], 0]
  if (len >= Sn) atomicAdd(&cnt, 1);
  __syncthreads();
  if (b == 0) bs_last[0] = cnt;
}

// ---------------- K3: split-K GEMM for gates i,g,o (f skipped: f*c0 == 0) ----------------
// grid = 32 m-tiles x 8 k-chunks = 256 blocks, 256 threads (4 waves).
// Layer 0: xt == emb and tok != nullptr -> rows gathered via tok_sorted (gather fused).
// thread owns 4 consecutive rows r and 12 gate columns (4 m x {i,g,o}).
// partials[kc][q][m][r], q in {0:i,1:g,2:o}
__global__ __launch_bounds__(256) void gemm_kernel(const float* __restrict__ xt,
                                                   const int* __restrict__ tok,
                                                   const float* __restrict__ Wl,
                                                   float* __restrict__ part) {
  __shared__ float xtT[32][132];  // [kk][r], stride 132 keeps 16B alignment for b128 reads
  __shared__ float Ws[32][96];    // [kk][q*32 + mloc]
  __shared__ int sTok[128];
  const int t = threadIdx.x;
  const int mtile = blockIdx.x & 31;
  const int kc = blockIdx.x >> 5;
  const int rg = t & 31;
  const int msub = t >> 5;     // 0..7 -> m_loc = msub*4..+3
  const int k0 = kc * 128;
  const int kv4 = (t & 7) * 4;

  if (tok != nullptr) {        // uniform branch; layer 0 only
    if (t < 128) sTok[t] = tok[t];
    __syncthreads();
  }
  const float* xrow[4];
#pragma unroll
  for (int i = 0; i < 4; i++) {
    const int r = i * 32 + (t >> 3);
    const int row = (tok != nullptr) ? sTok[r] : r;
    xrow[i] = xt + (size_t)row * 1024;
  }

  float acc[3][4][4];
#pragma unroll
  for (int q = 0; q < 3; q++)
#pragma unroll
    for (int mm = 0; mm < 4; mm++)
#pragma unroll
      for (int rr = 0; rr < 4; rr++) acc[q][mm][rr] = 0.0f;

  float4 xreg[4], wreg[3];
  // prologue: load tile 0 into registers
  {
#pragma unroll
    for (int i = 0; i < 4; i++) xreg[i] = *(const float4*)&xrow[i][k0 + kv4];
#pragma unroll
    for (int i = 0; i < 3; i++) {
      int jj = i * 32 + (t >> 3);
      int q = jj >> 5, mloc = jj & 31;
      int qoff = (q == 0) ? 0 : ((q == 1) ? 2048 : 3072);  // gate rows: i, g, o
      wreg[i] = *(const float4*)&Wl[(size_t)(qoff + mtile * 32 + mloc) * 1024 + k0 + kv4];
    }
  }

#pragma unroll
  for (int tile = 0; tile < 4; tile++) {
    __syncthreads();
    // registers -> LDS (transposed)
#pragma unroll
    for (int i = 0; i < 4; i++) {
      const int r = i * 32 + (t >> 3);
      xtT[kv4 + 0][r] = xreg[i].x;
      xtT[kv4 + 1][r] = xreg[i].y;
      xtT[kv4 + 2][r] = xreg[i].z;
      xtT[kv4 + 3][r] = xreg[i].w;
    }
#pragma unroll
    for (int i = 0; i < 3; i++) {
      const int jj = i * 32 + (t >> 3);
      Ws[kv4 + 0][jj] = wreg[i].x;
      Ws[kv4 + 1][jj] = wreg[i].y;
      Ws[kv4 + 2][jj] = wreg[i].z;
      Ws[kv4 + 3][jj] = wreg[i].w;
    }
    // prefetch next tile while computing this one
    float4 xnxt[4], wnxt[3];
    if (tile < 3) {
      const int kt = k0 + (tile + 1) * 32;
#pragma unroll
      for (int i = 0; i < 4; i++) xnxt[i] = *(const float4*)&xrow[i][kt + kv4];
#pragma unroll
      for (int i = 0; i < 3; i++) {
        int jj = i * 32 + (t >> 3);
        int q = jj >> 5, mloc = jj & 31;
        int qoff = (q == 0) ? 0 : ((q == 1) ? 2048 : 3072);
        wnxt[i] = *(const float4*)&Wl[(size_t)(qoff + mtile * 32 + mloc) * 1024 + kt + kv4];
      }
    }
    __syncthreads();
#pragma unroll
    for (int kk = 0; kk < 32; kk++) {
      const float4 xv = *(const float4*)&xtT[kk][rg * 4];
      const float4 w0 = *(const float4*)&Ws[kk][msub * 4];
      const float4 w1 = *(const float4*)&Ws[kk][32 + msub * 4];
      const float4 w2 = *(const float4*)&Ws[kk][64 + msub * 4];
      const float xa[4] = {xv.x, xv.y, xv.z, xv.w};
      const float wv[3][4] = {{w0.x, w0.y, w0.z, w0.w},
                              {w1.x, w1.y, w1.z, w1.w},
                              {w2.x, w2.y, w2.z, w2.w}};
#pragma unroll
      for (int q = 0; q < 3; q++)
#pragma unroll
        for (int mm = 0; mm < 4; mm++)
#pragma unroll
          for (int rr = 0; rr < 4; rr++)
            acc[q][mm][rr] = fmaf(wv[q][mm], xa[rr], acc[q][mm][rr]);
    }
    if (tile < 3) {
#pragma unroll
      for (int i = 0; i < 4; i++) xreg[i] = xnxt[i];
#pragma unroll
      for (int i = 0; i < 3; i++) wreg[i] = wnxt[i];
    }
  }

  const int mbase = mtile * 32 + msub * 4;
#pragma unroll
  for (int q = 0; q < 3; q++)
#pragma unroll
    for (int mm = 0; mm < 4; mm++) {
      float4 v = make_float4(acc[q][mm][0], acc[q][mm][1], acc[q][mm][2], acc[q][mm][3]);
      *(float4*)&part[(((size_t)kc * 3 + q) * 1024 + (mbase + mm)) * 128 + rg * 4] = v;
    }
}

// ---------------- K4: reduce partials + biases, activations, states ----------------
// grid = 256 blocks (4 m each), 256 threads: kc split 4+4 across thread halves
// (verified logic from R4 phase 3), LDS combine, half 0 applies activations + stores.
// 2x the waves of the 128-thread version -> hides the 12.6 MB gather latency.
__global__ __launch_bounds__(256) void act_kernel(const float* __restrict__ part,
                                                  const float* __restrict__ bih,
                                                  const float* __restrict__ bhh,
                                                  const int* __restrict__ bs_last,
                                                  float* __restrict__ xt_out,
                                                  float* __restrict__ sh,
                                                  float* __restrict__ sc) {
  __shared__ float red[128][12];
  const int t = threadIdx.x;
  const int r = t & 127;
  const int half = t >> 7;           // 0: kc 0-3, 1: kc 4-7
  const int m0 = blockIdx.x * 4;     // 256 blocks -> m in [0,1024) exactly
  float s[3][4];
#pragma unroll
  for (int q = 0; q < 3; q++)
#pragma unroll
    for (int mm = 0; mm < 4; mm++) s[q][mm] = 0.0f;
#pragma unroll
  for (int k4 = 0; k4 < 4; k4++) {
    const int kcc = half * 4 + k4;
#pragma unroll
    for (int q = 0; q < 3; q++)
#pragma unroll
      for (int mm = 0; mm < 4; mm++)
        s[q][mm] += part[(((size_t)kcc * 3 + q) * 1024 + (m0 + mm)) * 128 + r];
  }
  if (half == 1) {
#pragma unroll
    for (int q = 0; q < 3; q++)
#pragma unroll
      for (int mm = 0; mm < 4; mm++) red[r][q * 4 + mm] = s[q][mm];
  }
  __syncthreads();
  if (half == 0) {
    const int bs = bs_last[0];
    float hv[4], cv[4];
#pragma unroll
    for (int mm = 0; mm < 4; mm++) {
      const int m = m0 + mm;
      const float si = s[0][mm] + red[r][0 * 4 + mm] + bih[m] + bhh[m];
      const float sg = s[1][mm] + red[r][1 * 4 + mm] + bih[2048 + m] + bhh[2048 + m];
      const float so = s[2][mm] + red[r][2 * 4 + mm] + bih[3072 + m] + bhh[3072 + m];
      const float c = sigmoidf_(si) * tanhf(sg);
      const float h = sigmoidf_(so) * tanhf(c);
      hv[mm] = h;
      cv[mm] = c;
    }
    const float msk = (r < bs) ? 1.0f : 0.0f;
    *(float4*)&xt_out[(size_t)r * 1024 + m0] = make_float4(hv[0], hv[1], hv[2], hv[3]);
    *(float4*)&sh[(size_t)r * 1024 + m0] =
        make_float4(msk * hv[0], msk * hv[1], msk * hv[2], msk * hv[3]);
    *(float4*)&sc[(size_t)r * 1024 + m0] =
        make_float4(msk * cv[0], msk * cv[1], msk * cv[2], msk * cv[3]);
  }
}

// ---------------- K5: output[t,b,:] = (t < len[b]) ? h_final_sorted[rank[b],:] : 0 ----------------
// grid = 128 b x 8 t-chunks (64 t each). h row loaded ONCE per block into registers,
// then 64 x 4KB contiguous nontemporal stores.
__global__ __launch_bounds__(256) void bcast_kernel(const float* __restrict__ hfin,
                                                    const int* __restrict__ lengths,
                                                    const int* __restrict__ rank,
                                                    float* __restrict__ out) {
  const int b = blockIdx.x & 127;
  const int c = blockIdx.x >> 7;      // 0..7
  const int len = lengths[b];
  const int t0 = c * 64;
  nfloat4 v = (nfloat4)0.0f;
  if (t0 < len) v = ((const nfloat4*)hfin)[rank[b] * 256 + threadIdx.x];
  int valid = len - t0;
  valid = valid < 0 ? 0 : (valid > 64 ? 64 : valid);
  nfloat4* p = (nfloat4*)out + ((size_t)t0 * 128 + b) * 256 + threadIdx.x;
  for (int i = 0; i < valid; i++) {
    __builtin_nontemporal_store(v, p);
    p += 32768;                        // one t step = 128*1024 floats
  }
  const nfloat4 z = (nfloat4)0.0f;
  for (int i = valid; i < 64; i++) {
    __builtin_nontemporal_store(z, p);
    p += 32768;
  }
}

extern "C" void kernel_launch(void* const* d_in, const int* in_sizes, int n_in,
                              void* d_out, int out_size, void* d_ws, size_t ws_size,
                              hipStream_t stream) {
  const int* x = (const int*)d_in[0];
  const float* emb = (const float*)d_in[1];
  const float* W_ih = (const float*)d_in[2];
  // d_in[3] = W_hh: NEVER multiplied (h0 == 0); only b_hh is added.
  const float* b_ih = (const float*)d_in[4];
  const float* b_hh = (const float*)d_in[5];

  float* out = (float*)d_out;
  float* sh = out + (size_t)Sn * Bn * Hn;   // state_h [L,B,H]
  float* sc = sh + (size_t)Ln * Bn * Hn;    // state_c [L,B,H]
  float* part = out;                        // 12 MB GEMM-partial scratch inside the
                                            // output region; overwritten by bcast later.

  char* ws = (char*)d_ws;
  int* lengths = (int*)ws;                  // [128]
  int* rank = lengths + 128;                // [128]
  int* tok_sorted = rank + 128;             // [128]
  int* bs_last = tok_sorted + 128;          // [1]
  float* xtA = (float*)(ws + 4096);         // [128,1024]
  float* xtB = xtA + 128 * 1024;            // [128,1024]

  len_kernel<<<128, 128, 0, stream>>>(x, lengths);
  sort_kernel<<<1, 128, 0, stream>>>(x, lengths, rank, tok_sorted, bs_last);

  // layer 0 consumes emb rows gathered via tok_sorted directly (no gather kernel)
  float* bufs[2] = {xtA, xtB};
  const float* xin = emb;
  const int* tokp = tok_sorted;
  for (int l = 0; l < Ln; l++) {
    gemm_kernel<<<256, 256, 0, stream>>>(xin, tokp, W_ih + (size_t)l * 4 * Hn * Hn, part);
    act_kernel<<<256, 256, 0, stream>>>(part, b_ih + l * 4 * Hn, b_hh + l * 4 * Hn, bs_last,
                                        bufs[l & 1], sh + (size_t)l * Bn * Hn,
                                        sc + (size_t)l * Bn * Hn);
    xin = bufs[l & 1];
    tokp = nullptr;
  }
  // after the loop, xin == xtB holds the top-layer h (sorted order)
  bcast_kernel<<<1024, 256, 0, stream>>>(xin, lengths, rank, out);
}

// Round 7
// 475.876 us; speedup vs baseline: 1.5257x; 1.0405x over previous
//
#include <hip/hip_runtime.h>

#define Bn 128
#define Sn 512
#define Hn 1024
#define Ln 4

typedef float nfloat4 __attribute__((ext_vector_type(4)));
typedef __attribute__((ext_vector_type(8))) short short8;
typedef __attribute__((ext_vector_type(4))) float f32x4;

__device__ __forceinline__ float sigmoidf_(float x) { return 1.0f / (1.0f + __expf(-x)); }

// round-to-nearest-even fp32 -> bf16 (bit pattern in ushort)
__device__ __forceinline__ unsigned short bf16hi(float f) {
  unsigned u = __float_as_uint(f);
  u = u + 0x7FFFu + ((u >> 16) & 1u);
  return (unsigned short)(u >> 16);
}
__device__ __forceinline__ float bf16tof(unsigned short h) {
  return __uint_as_float(((unsigned)h) << 16);
}

// ---------------- K1: lengths[b] = count(x[b,:] > 0) ----------------
__global__ __launch_bounds__(128) void len_kernel(const int* __restrict__ x, int* __restrict__ lengths) {
  const int b = blockIdx.x, t = threadIdx.x;
  int4 v = ((const int4*)x)[b * 128 + t];
  int c = (v.x > 0) + (v.y > 0) + (v.z > 0) + (v.w > 0);
  for (int off = 32; off > 0; off >>= 1) c += __shfl_down(c, off);
  __shared__ int tmp[2];
  if ((t & 63) == 0) tmp[t >> 6] = c;
  __syncthreads();
  if (t == 0) lengths[b] = tmp[0] + tmp[1];
}

// ------- K2: stable descending argsort rank, sorted first tokens, bs_last -------
__global__ __launch_bounds__(128) void sort_kernel(const int* __restrict__ x, const int* __restrict__ lengths,
                                                   int* __restrict__ rank, int* __restrict__ tok_sorted,
                                                   int* __restrict__ bs_last) {
  __shared__ int sl[128];
  __shared__ int cnt;
  const int b = threadIdx.x;
  const int len = lengths[b];
  sl[b] = len;
  if (b == 0) cnt = 0;
  __syncthreads();
  int r = 0;
  for (int b2 = 0; b2 < 128; b2++) {
    int l2 = sl[b2];
    r += (l2 > len) || (l2 == len && b2 < b);
  }
  rank[b] = r;
  tok_sorted[r] = x[b * Sn];
  if (len >= Sn) atomicAdd(&cnt, 1);
  __syncthreads();
  if (b == 0) bs_last[0] = cnt;
}

// ---------------- K3: gather emb rows (sorted) + split to bf16 hi/lo ----------------
__global__ __launch_bounds__(256) void gather_cvt(const int* __restrict__ tok_sorted,
                                                  const float* __restrict__ emb,
                                                  unsigned short* __restrict__ xhi,
                                                  unsigned short* __restrict__ xlo) {
  const int r = blockIdx.x, t = threadIdx.x;
  const int tok = tok_sorted[r];
  float4 v = ((const float4*)emb)[(size_t)tok * 256 + t];
  float f[4] = {v.x, v.y, v.z, v.w};
  unsigned short hh[4], ll[4];
#pragma unroll
  for (int j = 0; j < 4; j++) {
    hh[j] = bf16hi(f[j]);
    ll[j] = bf16hi(f[j] - bf16tof(hh[j]));
  }
  ((ushort4*)xhi)[r * 256 + t] = make_ushort4(hh[0], hh[1], hh[2], hh[3]);
  ((ushort4*)xlo)[r * 256 + t] = make_ushort4(ll[0], ll[1], ll[2], ll[3]);
}

// ---------------- K4: MFMA split-K GEMM, bf16x3 fp32 emulation ----------------
// grid = 48 n-tiles (64 gate-cols) x 4 k-chunks (K=256) = 192 blocks, 256 threads (4 waves).
// gates[r][j] = sum_k x[r][k]*W[row(j)][k], j in 64-col tile within one gate q (i,g,o).
// W chunk (64x256 fp32) -> LDS bf16 hi/lo once; A-frags read straight from global bf16 x.
// Fragment maps (gfx950 16x16x32): A row=lane&15, k=(lane>>4)*8+j; B col=lane&15, same k;
// D col=lane&15, row=(lane>>4)*4+reg  [m89-verified].
// partials[kc][q][m][r] identical addressing to act_kernel.
__global__ __launch_bounds__(256) void gemm_mfma(const unsigned short* __restrict__ xhi,
                                                 const unsigned short* __restrict__ xlo,
                                                 const float* __restrict__ Wl,
                                                 float* __restrict__ part) {
  __shared__ unsigned short Whi[64][264];  // 256 + 8 pad: 8 distinct 16B bank-starts on frag reads
  __shared__ unsigned short Wlo[64][264];
  const int t = threadIdx.x;
  const int bid = blockIdx.x;
  const int nt = bid % 48;
  const int kc = bid / 48;
  const int q = nt >> 4;                              // 0:i 1:g 2:o
  const int qoff = (q == 0) ? 0 : ((q == 1) ? 2048 : 3072);
  const int mrow0 = qoff + (nt & 15) * 64;            // W row base of this 64-col tile
  const int k0 = kc * 256;

  // stage + convert W[64][256] fp32 -> bf16 hi/lo in LDS (each W element read once globally)
#pragma unroll
  for (int i = 0; i < 16; i++) {
    const int vi = i * 256 + t;
    const int c = vi >> 6;          // 0..63
    const int ks4 = (vi & 63) * 4;  // 0..252
    float4 w4 = *(const float4*)&Wl[(size_t)(mrow0 + c) * 1024 + k0 + ks4];
    float f[4] = {w4.x, w4.y, w4.z, w4.w};
    unsigned short hh[4], ll[4];
#pragma unroll
    for (int j = 0; j < 4; j++) {
      hh[j] = bf16hi(f[j]);
      ll[j] = bf16hi(f[j] - bf16tof(hh[j]));
    }
    *(ushort4*)&Whi[c][ks4] = make_ushort4(hh[0], hh[1], hh[2], hh[3]);
    *(ushort4*)&Wlo[c][ks4] = make_ushort4(ll[0], ll[1], ll[2], ll[3]);
  }
  __syncthreads();

  const int w = t >> 6;         // wave 0..3 -> rows w*32..+31
  const int l = t & 63;
  const int lrow = l & 15;
  const int lk8 = (l >> 4) * 8;

  f32x4 acc[2][4];
#pragma unroll
  for (int rt = 0; rt < 2; rt++)
#pragma unroll
    for (int ct = 0; ct < 4; ct++) acc[rt][ct] = (f32x4)0.0f;

  const unsigned short* xh0 = xhi + (size_t)(w * 32 + lrow) * 1024 + k0 + lk8;
  const unsigned short* xl0 = xlo + (size_t)(w * 32 + lrow) * 1024 + k0 + lk8;

#pragma unroll
  for (int ks = 0; ks < 8; ks++) {
    const int kk = ks * 32;
    short8 ah[2], al[2], bh[4], bl[4];
#pragma unroll
    for (int rt = 0; rt < 2; rt++) {
      ah[rt] = *(const short8*)(xh0 + rt * 16 * 1024 + kk);
      al[rt] = *(const short8*)(xl0 + rt * 16 * 1024 + kk);
    }
#pragma unroll
    for (int ct = 0; ct < 4; ct++) {
      bh[ct] = *(const short8*)&Whi[ct * 16 + lrow][kk + lk8];
      bl[ct] = *(const short8*)&Wlo[ct * 16 + lrow][kk + lk8];
    }
#pragma unroll
    for (int rt = 0; rt < 2; rt++)
#pragma unroll
      for (int ct = 0; ct < 4; ct++) {
        acc[rt][ct] = __builtin_amdgcn_mfma_f32_16x16x32_bf16(ah[rt], bh[ct], acc[rt][ct], 0, 0, 0);
        acc[rt][ct] = __builtin_amdgcn_mfma_f32_16x16x32_bf16(ah[rt], bl[ct], acc[rt][ct], 0, 0, 0);
        acc[rt][ct] = __builtin_amdgcn_mfma_f32_16x16x32_bf16(al[rt], bh[ct], acc[rt][ct], 0, 0, 0);
      }
  }

  const int rbase = w * 32 + (l >> 4) * 4;   // + rt*16; regs map 4 consecutive r
#pragma unroll
  for (int rt = 0; rt < 2; rt++)
#pragma unroll
    for (int ct = 0; ct < 4; ct++) {
      const int m = (nt & 15) * 64 + ct * 16 + lrow;
      *(f32x4*)&part[(((size_t)kc * 3 + q) * 1024 + m) * 128 + rbase + rt * 16] = acc[rt][ct];
    }
}

// ---------------- K5: reduce 4 partials + biases, activations, states, bf16 split ----------------
// grid = 256 blocks (4 m each), 256 threads: kc split 2+2 across thread halves, LDS combine.
__global__ __launch_bounds__(256) void act_kernel(const float* __restrict__ part,
                                                  const float* __restrict__ bih,
                                                  const float* __restrict__ bhh,
                                                  const int* __restrict__ bs_last,
                                                  float* __restrict__ xt_out,
                                                  float* __restrict__ sh,
                                                  float* __restrict__ sc,
                                                  unsigned short* __restrict__ xhi_out,
                                                  unsigned short* __restrict__ xlo_out) {
  __shared__ float red[128][12];
  const int t = threadIdx.x;
  const int r = t & 127;
  const int half = t >> 7;           // 0: kc {0,1}, 1: kc {2,3}
  const int m0 = blockIdx.x * 4;     // 256 blocks -> m in [0,1024) exactly
  float s[3][4];
#pragma unroll
  for (int qq = 0; qq < 3; qq++)
#pragma unroll
    for (int mm = 0; mm < 4; mm++) s[qq][mm] = 0.0f;
#pragma unroll
  for (int k2 = 0; k2 < 2; k2++) {
    const int kcc = half * 2 + k2;
#pragma unroll
    for (int qq = 0; qq < 3; qq++)
#pragma unroll
      for (int mm = 0; mm < 4; mm++)
        s[qq][mm] += part[(((size_t)kcc * 3 + qq) * 1024 + (m0 + mm)) * 128 + r];
  }
  if (half == 1) {
#pragma unroll
    for (int qq = 0; qq < 3; qq++)
#pragma unroll
      for (int mm = 0; mm < 4; mm++) red[r][qq * 4 + mm] = s[qq][mm];
  }
  __syncthreads();
  if (half == 0) {
    const int bs = bs_last[0];
    float hv[4], cv[4];
    unsigned short hh[4], ll[4];
#pragma unroll
    for (int mm = 0; mm < 4; mm++) {
      const int m = m0 + mm;
      const float si = s[0][mm] + red[r][0 * 4 + mm] + bih[m] + bhh[m];
      const float sg = s[1][mm] + red[r][1 * 4 + mm] + bih[2048 + m] + bhh[2048 + m];
      const float so = s[2][mm] + red[r][2 * 4 + mm] + bih[3072 + m] + bhh[3072 + m];
      const float c = sigmoidf_(si) * tanhf(sg);
      const float h = sigmoidf_(so) * tanhf(c);
      hv[mm] = h;
      cv[mm] = c;
      hh[mm] = bf16hi(h);
      ll[mm] = bf16hi(h - bf16tof(hh[mm]));
    }
    const float msk = (r < bs) ? 1.0f : 0.0f;
    *(float4*)&xt_out[(size_t)r * 1024 + m0] = make_float4(hv[0], hv[1], hv[2], hv[3]);
    *(float4*)&sh[(size_t)r * 1024 + m0] =
        make_float4(msk * hv[0], msk * hv[1], msk * hv[2], msk * hv[3]);
    *(float4*)&sc[(size_t)r * 1024 + m0] =
        make_float4(msk * cv[0], msk * cv[1], msk * cv[2], msk * cv[3]);
    *(ushort4*)&xhi_out[(size_t)r * 1024 + m0] = make_ushort4(hh[0], hh[1], hh[2], hh[3]);
    *(ushort4*)&xlo_out[(size_t)r * 1024 + m0] = make_ushort4(ll[0], ll[1], ll[2], ll[3]);
  }
}

// ---------------- K6: output[t,b,:] = (t < len[b]) ? h_final_sorted[rank[b],:] : 0 ----------------
__global__ __launch_bounds__(256) void bcast_kernel(const float* __restrict__ hfin,
                                                    const int* __restrict__ lengths,
                                                    const int* __restrict__ rank,
                                                    float* __restrict__ out) {
  const int b = blockIdx.x & 127;
  const int c = blockIdx.x >> 7;      // 0..7
  const int len = lengths[b];
  const int t0 = c * 64;
  nfloat4 v = (nfloat4)0.0f;
  if (t0 < len) v = ((const nfloat4*)hfin)[rank[b] * 256 + threadIdx.x];
  int valid = len - t0;
  valid = valid < 0 ? 0 : (valid > 64 ? 64 : valid);
  nfloat4* p = (nfloat4*)out + ((size_t)t0 * 128 + b) * 256 + threadIdx.x;
  for (int i = 0; i < valid; i++) {
    __builtin_nontemporal_store(v, p);
    p += 32768;
  }
  const nfloat4 z = (nfloat4)0.0f;
  for (int i = valid; i < 64; i++) {
    __builtin_nontemporal_store(z, p);
    p += 32768;
  }
}

extern "C" void kernel_launch(void* const* d_in, const int* in_sizes, int n_in,
                              void* d_out, int out_size, void* d_ws, size_t ws_size,
                              hipStream_t stream) {
  const int* x = (const int*)d_in[0];
  const float* emb = (const float*)d_in[1];
  const float* W_ih = (const float*)d_in[2];
  // d_in[3] = W_hh: NEVER multiplied (h0 == 0); only b_hh is added.
  const float* b_ih = (const float*)d_in[4];
  const float* b_hh = (const float*)d_in[5];

  float* out = (float*)d_out;
  float* sh = out + (size_t)Sn * Bn * Hn;   // state_h [L,B,H]
  float* sc = sh + (size_t)Ln * Bn * Hn;    // state_c [L,B,H]
  float* part = out;                        // 6.3 MB partial scratch = out t-slabs [0,12)
  // bf16 hi/lo ping-pong buffers inside out region (t-slab 16+), overwritten by bcast at end
  unsigned short* bfbase = (unsigned short*)(out + (size_t)2097152);
  unsigned short* xhiA = bfbase;
  unsigned short* xloA = bfbase + 131072;
  unsigned short* xhiB = bfbase + 262144;
  unsigned short* xloB = bfbase + 393216;

  char* ws = (char*)d_ws;
  int* lengths = (int*)ws;                  // [128]
  int* rank = lengths + 128;                // [128]
  int* tok_sorted = rank + 128;             // [128]
  int* bs_last = tok_sorted + 128;          // [1]
  float* xtA = (float*)(ws + 4096);         // [128,1024] fp32 h (for bcast)
  float* xtB = xtA + 128 * 1024;

  len_kernel<<<128, 128, 0, stream>>>(x, lengths);
  sort_kernel<<<1, 128, 0, stream>>>(x, lengths, rank, tok_sorted, bs_last);
  gather_cvt<<<128, 256, 0, stream>>>(tok_sorted, emb, xhiA, xloA);

  float* xtF[2] = {xtA, xtB};
  unsigned short* hiP[2] = {xhiA, xhiB};
  unsigned short* loP[2] = {xloA, xloB};
  int cur = 0;
  for (int l = 0; l < Ln; l++) {
    const int nxt = cur ^ 1;
    gemm_mfma<<<192, 256, 0, stream>>>(hiP[cur], loP[cur], W_ih + (size_t)l * 4 * Hn * Hn, part);
    act_kernel<<<256, 256, 0, stream>>>(part, b_ih + l * 4 * Hn, b_hh + l * 4 * Hn, bs_last,
                                        xtF[l & 1], sh + (size_t)l * Bn * Hn,
                                        sc + (size_t)l * Bn * Hn, hiP[nxt], loP[nxt]);
    cur = nxt;
  }
  // top-layer h fp32 = xtF[3&1] = xtB
  bcast_kernel<<<1024, 256, 0, stream>>>(xtF[1], lengths, rank, out);
}